// Round 6
// baseline (353.056 us; speedup 1.0000x reference)
//
#include <hip/hip_runtime.h>
#include <math.h>

#define T_SEQ 2048
#define D_MODEL 1024
#define NHEADS 16
#define HSZ 64
#define BATCH 4

typedef __bf16 bf16x8 __attribute__((ext_vector_type(8)));
typedef __bf16 bf16x4 __attribute__((ext_vector_type(4)));
typedef short short4v __attribute__((ext_vector_type(4)));
typedef float f32x4 __attribute__((ext_vector_type(4)));
typedef float f32x16 __attribute__((ext_vector_type(16)));

__device__ __forceinline__ unsigned short f2bf(float f) {
    unsigned int u = __builtin_bit_cast(unsigned int, f);
    u += 0x7fff + ((u >> 16) & 1);   // RNE
    return (unsigned short)(u >> 16);
}

// pack two fp32 -> two bf16 (RNE) in one reg
__device__ __forceinline__ unsigned int pk2bf(float a, float b) {
#if __has_builtin(__builtin_amdgcn_cvt_pk_bf16_f32)
    typedef __bf16 bf16x2_t __attribute__((ext_vector_type(2)));
    bf16x2_t v = __builtin_amdgcn_cvt_pk_bf16_f32(a, b);
    return __builtin_bit_cast(unsigned int, v);
#else
    return (unsigned int)f2bf(a) | ((unsigned int)f2bf(b) << 16);
#endif
}

// raw v_exp_f32 (domain bounded; denormal flush acceptable)
__device__ __forceinline__ float fexp2(float x) {
#if __has_builtin(__builtin_amdgcn_exp2f)
    return __builtin_amdgcn_exp2f(x);
#else
    return __builtin_exp2f(x);
#endif
}

// half-swap across the lane<32 / lane>=32 boundary (T12):
// a.new = (l<32) ? a : partner(l^32).b ;  b.new = (l<32) ? partner(l^32).a : b
__device__ __forceinline__ void pl32swap(unsigned int& a, unsigned int& b) {
#if __has_builtin(__builtin_amdgcn_permlane32_swap)
    auto r = __builtin_amdgcn_permlane32_swap((int)a, (int)b, false, false);
    a = (unsigned int)r[0];
    b = (unsigned int)r[1];
#else
    unsigned int sa = (unsigned int)__shfl_xor((int)a, 32);
    unsigned int sb = (unsigned int)__shfl_xor((int)b, 32);
    const int hi = (int)((threadIdx.x & 63) >> 5);
    unsigned int na = hi ? sb : a;
    unsigned int nb = hi ? b : sa;
    a = na; b = nb;
#endif
}

__device__ __forceinline__ void gld_lds16(const void* g, void* lds) {
    __builtin_amdgcn_global_load_lds(
        (const __attribute__((address_space(1))) unsigned int*)g,
        (__attribute__((address_space(3))) unsigned int*)lds, 16, 0, 0);
}

__device__ __forceinline__ bf16x8 ld8(const unsigned short* p) {
    return *(const bf16x8*)p;
}

// T5 bucket bias (log2e-scaled), identical math to the reference bucketing.
__device__ __forceinline__ float t5_bias(int delta, int h, const float* __restrict__ rel) {
    int bucket = delta > 0 ? 16 : 0;
    int arp = delta < 0 ? -delta : delta;
    if (arp < 8) {
        bucket += arp;
    } else {
        float f = logf((float)arp / 7.0f) * (8.0f / logf(128.0f / 7.0f));
        int rl = 7 + (int)f;            // trunc == floor (f>0)
        bucket += rl < 15 ? rl : 15;
    }
    return rel[bucket * NHEADS + h] * 1.4426950408889634f;
}

// ---------------- fused prep: cast X (bf16), cast W (bf16) --------------------------
// grid: [0,8192) cast_x | [8192,12288) cast_w
__global__ void prep(const float* __restrict__ x,
                     const float* __restrict__ w0, const float* __restrict__ w1,
                     const float* __restrict__ w2, const float* __restrict__ w3,
                     unsigned short* __restrict__ Xbf,
                     unsigned short* __restrict__ Wbf) {
    int bid = blockIdx.x;
    int tid = threadIdx.x;
    if (bid < 8192) {
        int i = bid * 256 + tid;            // 2097152 float4s
        float4 v = ((const float4*)x)[i];
        ushort4 o;
        o.x = f2bf(v.x); o.y = f2bf(v.y); o.z = f2bf(v.z); o.w = f2bf(v.w);
        ((ushort4*)Xbf)[i] = o;
    } else {
        int wsel = (bid - 8192) >> 10;
        const float* srcs[4] = {w0, w1, w2, w3};
        int i = ((bid - 8192) & 1023) * 256 + tid;   // 262144 float4s per W
        float4 v = ((const float4*)srcs[wsel])[i];
        ushort4 o;
        o.x = f2bf(v.x); o.y = f2bf(v.y); o.z = f2bf(v.z); o.w = f2bf(v.w);
        ((ushort4*)(Wbf + (size_t)wsel * 1048576))[i] = o;
    }
}

// ---------------- GEMM: C[M,N] = A[M,K] * B[N,K]^T  (bf16 in, fp32 acc) -------------
// v10: double-buffered K-loop (1 barrier/kt, prefetch overlaps MFMA) + XCD-aware
// bijective block swizzle (T1). LDS 2 x 32 KB = 64 KB -> still 2 blocks/CU.
// MODE 4: merged QKV.  B = [Wq;Wk;Wv] (3072x1024).  out = Q base; K at +8M, Vt at +16M.
// MODE 3: plain fp32 [M,1024] (output projection)
template<int MODE>
__global__ __launch_bounds__(256, 2) void gemm_bt(
    const unsigned short* __restrict__ A,
    const unsigned short* __restrict__ Bw,
    void* __restrict__ out)
{
    constexpr int K = 1024;
    __shared__ __align__(16) char smem[65536];   // 2 x (As 16K + Bs 16K)

    const int tid  = threadIdx.x;
    const int wave = tid >> 6;
    const int lane = tid & 63;
    const int quad = lane >> 4;
    const int l16  = lane & 15;
    const int wm   = wave >> 1;
    const int wn   = wave & 1;

    // XCD-aware bijective swizzle: nwg % 8 == 0 in both modes.
    constexpr int NWGX = (MODE == 4) ? 24 : 8;
    const int orig = blockIdx.x + blockIdx.y * NWGX;
    constexpr int CPX = (NWGX * 64) / 8;     // chunk per XCD
    const int swz  = (orig & 7) * CPX + (orig >> 3);
    const int bn   = swz % NWGX;
    const int bm   = swz / NWGX;

    const int r_in = lane >> 3;              // 0..7
    const int lc   = (lane & 7) ^ r_in;      // swizzled 16B chunk

    f32x4 acc[4][4];
    #pragma unroll
    for (int m = 0; m < 4; ++m)
        #pragma unroll
        for (int n = 0; n < 4; ++n)
            acc[m][n] = f32x4{0.f, 0.f, 0.f, 0.f};

    const long a_row0 = (long)bm * 128;
    const long b_row0 = (long)bn * 128;

    // prologue: stage tile 0 into buffer 0
    {
        const int k0 = lc * 8;
        unsigned short* As_ = (unsigned short*)smem;
        unsigned short* Bs_ = (unsigned short*)(smem + 16384);
        #pragma unroll
        for (int c = 0; c < 4; ++c) {
            int cc = wave * 4 + c;
            int r  = cc * 8 + r_in;
            gld_lds16(A  + (a_row0 + r) * K + k0, &As_[cc * 512]);
            gld_lds16(Bw + (b_row0 + r) * K + k0, &Bs_[cc * 512]);
        }
    }

    for (int kt = 0; kt < K / 64; ++kt) {
        const int cur = kt & 1;
        __syncthreads();   // vmcnt(0): buf[cur] staged; all prev-buffer reads done

        if (kt + 1 < K / 64) {   // prefetch next K-tile into the other buffer
            const int k0 = (kt + 1) * 64 + lc * 8;
            unsigned short* As_ = (unsigned short*)(smem + (cur ^ 1) * 32768);
            unsigned short* Bs_ = (unsigned short*)(smem + (cur ^ 1) * 32768 + 16384);
            #pragma unroll
            for (int c = 0; c < 4; ++c) {
                int cc = wave * 4 + c;
                int r  = cc * 8 + r_in;
                gld_lds16(A  + (a_row0 + r) * K + k0, &As_[cc * 512]);
                gld_lds16(Bw + (b_row0 + r) * K + k0, &Bs_[cc * 512]);
            }
        }

        unsigned short* As = (unsigned short*)(smem + cur * 32768);
        unsigned short* Bs = (unsigned short*)(smem + cur * 32768 + 16384);

        bf16x8 af[4][2], bf[4][2];
        #pragma unroll
        for (int m = 0; m < 4; ++m)
            #pragma unroll
            for (int ks = 0; ks < 2; ++ks) {
                int r  = wm * 64 + m * 16 + l16;
                int pc = (ks * 4 + quad) ^ (r & 7);
                af[m][ks] = ld8(&As[r * 64 + pc * 8]);
            }
        #pragma unroll
        for (int n = 0; n < 4; ++n)
            #pragma unroll
            for (int ks = 0; ks < 2; ++ks) {
                int r  = wn * 64 + n * 16 + l16;
                int pc = (ks * 4 + quad) ^ (r & 7);
                bf[n][ks] = ld8(&Bs[r * 64 + pc * 8]);
            }
        #pragma unroll
        for (int ks = 0; ks < 2; ++ks)
            #pragma unroll
            for (int m = 0; m < 4; ++m)
                #pragma unroll
                for (int n = 0; n < 4; ++n)
                    acc[m][n] = __builtin_amdgcn_mfma_f32_16x16x32_bf16(
                        af[m][ks], bf[n][ks], acc[m][n], 0, 0, 0);
    }

    // epilogue: C/D layout col = lane&15, row = quad*4 + reg
    const int which = (MODE == 4) ? (bn >> 3) : 0;   // block-uniform: 0=Q 1=K 2=V
    if (MODE == 3) {
        float* O = (float*)out;
        #pragma unroll
        for (int m = 0; m < 4; ++m) {
            int row = bm * 128 + wm * 64 + m * 16 + quad * 4;
            #pragma unroll
            for (int n = 0; n < 4; ++n) {
                int col = bn * 128 + wn * 64 + n * 16 + l16;
                #pragma unroll
                for (int r = 0; r < 4; ++r)
                    O[(long)(row + r) * 1024 + col] = acc[m][n][r];
            }
        }
    } else if (which == 2) {
        // V: r-packed ushort4 direct to [B,NH,HS,T]
        unsigned short* O = (unsigned short*)out + (size_t)2 * 8388608;
        #pragma unroll
        for (int m = 0; m < 4; ++m) {
            int row = bm * 128 + wm * 64 + m * 16 + quad * 4;
            int b = row >> 11, t = row & 2047;
            #pragma unroll
            for (int n = 0; n < 4; ++n) {
                int cl = (bn * 128 + wn * 64 + n * 16 + l16) & 1023;
                int h = cl >> 6, hs = cl & 63;
                ushort4 pk;
                pk.x = f2bf(acc[m][n][0]); pk.y = f2bf(acc[m][n][1]);
                pk.z = f2bf(acc[m][n][2]); pk.w = f2bf(acc[m][n][3]);
                *(ushort4*)&O[(long)((b * 16 + h) * 64 + hs) * 2048 + t] = pk;
            }
        }
    } else {
        // Q/K: per-wave LDS transpose -> contiguous dwordx4 stores to [B,NH,T,HS].
        __syncthreads();   // all waves done with As/Bs k-loop reads
        unsigned short* Ew = (unsigned short*)smem + wave * 4608;   // 64 x 72-stride
        const float qs = (which == 0) ? 0.125f * 1.4426950408889634f : 1.0f;
        #pragma unroll
        for (int m = 0; m < 4; ++m)
            #pragma unroll
            for (int n = 0; n < 4; ++n)
                #pragma unroll
                for (int r = 0; r < 4; ++r)
                    Ew[(m * 16 + quad * 4 + r) * 72 + n * 16 + l16] =
                        f2bf(acc[m][n][r] * qs);
        asm volatile("s_waitcnt lgkmcnt(0)" ::: "memory");  // wave-private write->read

        const int cl0 = (bn * 128 + wn * 64) & 1023;
        const int h   = cl0 >> 6;
        const int gr0 = bm * 128 + wm * 64;
        const int b   = gr0 >> 11, t0 = gr0 & 2047;
        unsigned short* O = (unsigned short*)out + (size_t)which * 8388608
                          + ((size_t)(b * 16 + h) * 2048 + t0) * 64;
        #pragma unroll
        for (int rr = 0; rr < 8; ++rr) {
            int row   = rr * 8 + (lane >> 3);
            int chunk = lane & 7;
            uint4 v = *(const uint4*)&Ew[row * 72 + chunk * 8];
            *(uint4*)&O[(size_t)row * 64 + chunk * 8] = v;
        }
    }
}

// ---------------- flash attention v11: 64 q-rows per wave, KVBLK=128 -----------------
// v9 -> v11: each wave owns TWO 32-q tiles (128 apart) -> K/V LDS fragments (af/vf,
// identical across waves AND q-tiles) amortize over 2x the output: LDS reads per
// token-q halve. KVBLK 64 -> 128 halves barrier/vmcnt-drain count. QBLK=256,
// grid 8x64 = 512 blocks, 2 blocks/CU, 2 waves/SIMD (VGPR-capped via lb(256,2)).
// LDS: Ks dbuf 32K + Vs dbuf 32K + Bb 1.1K = 65.1 KB.
__global__ __launch_bounds__(256, 2) void attn(
    const unsigned short* __restrict__ Q,    // [B,NH,T,HS] bf16, pre-scaled by 0.125*log2e
    const unsigned short* __restrict__ Kb,   // [B,NH,T,HS] bf16
    const unsigned short* __restrict__ Vt,   // [B,NH,HS,T] bf16
    const float* __restrict__ rel,           // [N_BUCKETS, NH] fp32 (input buffer)
    unsigned short* __restrict__ AO)         // [B,T,D] bf16
{
    __shared__ __align__(16) char smem[66592];
    unsigned short* KsB = (unsigned short*)smem;             // 2 x 16 KB (128 tok x 64 hs)
    unsigned short* VsB = (unsigned short*)(smem + 32768);   // 2 x 16 KB (64 hs x 128 tok)
    float*          Bb  = (float*)(smem + 65536);            // 263 floats delta-table

    const int tid  = threadIdx.x;
    const int wave = tid >> 6;
    const int lane = tid & 63;
    const int l31  = lane & 31;
    const int h5   = lane >> 5;

    const int bh = blockIdx.y;          // b*16 + h
    const int b  = bh >> 4, h = bh & 15;
    const int q0 = blockIdx.x * 256;

    const unsigned short* Qg = Q  + (long)bh * T_SEQ * HSZ;
    const unsigned short* Kg = Kb + (long)bh * T_SEQ * HSZ;
    const unsigned short* Vg = Vt + (long)bh * HSZ * T_SEQ;

    // K staging mapping: cc in [0,16) covers rows cc*8 + r_in; chunk lc pre-swizzled
    const int r_in = lane >> 3;
    const int lc   = (lane & 7) ^ r_in;
    // V staging mapping: cc in [0,16) covers rows cc*4 + (lane>>4); 16 chunks/row
    const int vr_l = lane >> 4;          // 0..3

    // prefetch tile 0 into buffer 0
    {
        #pragma unroll
        for (int c = 0; c < 4; ++c) {
            int cc = wave * 4 + c;
            int kr = cc * 8 + r_in;
            gld_lds16(Kg + (long)kr * 64 + lc * 8, &KsB[cc * 512]);
            int vr = cc * 4 + vr_l;
            int vch = (lane & 15) ^ (vr & 7);
            gld_lds16(Vg + (long)vr * T_SEQ + vch * 8, &VsB[cc * 512]);
        }
    }

    // delta-table: Bb[i] = bias(delta = i - 131), i in [0,263). Saturation at the
    // edges makes clamped reads bit-identical to the full sliding window.
    for (int i = tid; i < 263; i += 256)
        Bb[i] = t5_bias(i - 131, h, rel);

    // Q fragments: two q-tiles per wave (qt=0: q0+w*32+l31, qt=1: +128)
    bf16x8 qf[2][4];
    #pragma unroll
    for (int qt = 0; qt < 2; ++qt) {
        const int qrow = q0 + qt * 128 + wave * 32 + l31;
        #pragma unroll
        for (int hsc = 0; hsc < 4; ++hsc)
            qf[qt][hsc] = ld8(&Qg[(long)qrow * 64 + hsc * 16 + h5 * 8]);
    }

    f32x16 o[2][2];   // [qt][hst]
    float li[2] = {0.f, 0.f};
    #pragma unroll
    for (int qt = 0; qt < 2; ++qt)
        #pragma unroll
        for (int hst = 0; hst < 2; ++hst)
            o[qt][hst] = f32x16{0.f,0.f,0.f,0.f,0.f,0.f,0.f,0.f,
                                0.f,0.f,0.f,0.f,0.f,0.f,0.f,0.f};

    // saturated buckets: delta <= -128 -> bucket 15; delta >= +128 -> bucket 31
    const float cneg = rel[15 * NHEADS + h] * 1.4426950408889634f;
    const float cpos = rel[31 * NHEADS + h] * 1.4426950408889634f;

    for (int kt = 0; kt < T_SEQ / 128; ++kt) {
        const int cur = kt & 1;
        __syncthreads();   // vmcnt(0): cur buffer staged; all prev-buffer reads done

        if (kt + 1 < T_SEQ / 128) {          // prefetch next tile into other buffer
            unsigned short* Kn = KsB + (cur ^ 1) * 8192;
            unsigned short* Vn = VsB + (cur ^ 1) * 8192;
            #pragma unroll
            for (int c = 0; c < 4; ++c) {
                int cc = wave * 4 + c;
                int kr = cc * 8 + r_in;
                gld_lds16(Kg + (long)((kt + 1) * 128 + kr) * 64 + lc * 8, &Kn[cc * 512]);
                int vr = cc * 4 + vr_l;
                int vch = (lane & 15) ^ (vr & 7);
                gld_lds16(Vg + (long)vr * T_SEQ + (kt + 1) * 128 + vch * 8, &Vn[cc * 512]);
            }
        }

        const unsigned short* Ks = KsB + cur * 8192;
        const unsigned short* Vs = VsB + cur * 8192;

        #pragma unroll
        for (int tt = 0; tt < 4; ++tt) {
            const int tok_lo = kt * 128 + tt * 32;

            // ---- K fragments (shared across both q-tiles) ----
            const int rk = tt * 32 + l31;
            bf16x8 af[4];
            #pragma unroll
            for (int hsc = 0; hsc < 4; ++hsc)
                af[hsc] = ld8(&Ks[rk * 64 + (((hsc << 1) | h5) ^ (rk & 7)) * 8]);

            bf16x8 pf[2][2];
            #pragma unroll
            for (int qt = 0; qt < 2; ++qt) {
                const int qlo = q0 + qt * 128 + wave * 32;
                const int dmin = tok_lo - qlo - 31;
                const int dmax = tok_lo + 31 - qlo;
                f32x16 s;
                if (dmin >= 128 || dmax <= -128) {
                    const float cb = (dmin >= 128) ? cpos : cneg;
                    #pragma unroll
                    for (int e = 0; e < 16; ++e) s[e] = cb;
                } else {
                    const int ibase = tok_lo + h5 * 4 + 131 - (qlo + l31);
                    #pragma unroll
                    for (int g = 0; g < 4; ++g) {
                        int i0 = ibase + g * 8;
                        i0 = i0 < 0 ? 0 : (i0 > 259 ? 259 : i0);
                        #pragma unroll
                        for (int r = 0; r < 4; ++r) s[g * 4 + r] = Bb[i0 + r];
                    }
                }

                // ---- St = K Q^T + bias ----
                __builtin_amdgcn_s_setprio(1);
                #pragma unroll
                for (int hsc = 0; hsc < 4; ++hsc)
                    s = __builtin_amdgcn_mfma_f32_32x32x16_bf16(af[hsc], qf[qt][hsc],
                                                                s, 0, 0, 0);
                __builtin_amdgcn_s_setprio(0);

                // ---- softmax numerators ----
                float p[16];
                #pragma unroll
                for (int e = 0; e < 16; ++e) p[e] = fexp2(s[e]);
                {   // 4-deep tree, single dependent add into li per tile
                    float t0 = (p[0]  + p[1])  + (p[2]  + p[3]);
                    float t1 = (p[4]  + p[5])  + (p[6]  + p[7]);
                    float t2 = (p[8]  + p[9])  + (p[10] + p[11]);
                    float t3 = (p[12] + p[13]) + (p[14] + p[15]);
                    li[qt] += (t0 + t1) + (t2 + t3);
                }

                // ---- pack + half-swap into PV A-frags ----
                unsigned int x0 = pk2bf(p[0],  p[1]),  x1 = pk2bf(p[2],  p[3]);
                unsigned int y0 = pk2bf(p[4],  p[5]),  y1 = pk2bf(p[6],  p[7]);
                unsigned int z0 = pk2bf(p[8],  p[9]),  z1 = pk2bf(p[10], p[11]);
                unsigned int u0 = pk2bf(p[12], p[13]), u1 = pk2bf(p[14], p[15]);
                pl32swap(x0, y0); pl32swap(x1, y1);
                pl32swap(z0, u0); pl32swap(z1, u1);
                uint4 pw0 = {x0, x1, y0, y1};
                uint4 pw1 = {z0, z1, u0, u1};
                pf[qt][0] = __builtin_bit_cast(bf16x8, pw0);
                pf[qt][1] = __builtin_bit_cast(bf16x8, pw1);
            }

            // ---- O += P V (V fragments shared across both q-tiles) ----
            #pragma unroll
            for (int c = 0; c < 2; ++c) {
                const int ts = tt * 2 + c;       // 16-token slice in [0,8)
                bf16x8 vf[2];
                #pragma unroll
                for (int hst = 0; hst < 2; ++hst) {
                    const int rv = hst * 32 + l31;
                    vf[hst] = ld8(&Vs[rv * 128 + ((ts * 2 + h5) ^ (rv & 7)) * 8]);
                }
                __builtin_amdgcn_s_setprio(1);
                #pragma unroll
                for (int qt = 0; qt < 2; ++qt) {
                    o[qt][0] = __builtin_amdgcn_mfma_f32_32x32x16_bf16(
                        pf[qt][c], vf[0], o[qt][0], 0, 0, 0);
                    o[qt][1] = __builtin_amdgcn_mfma_f32_32x32x16_bf16(
                        pf[qt][c], vf[1], o[qt][1], 0, 0, 0);
                }
                __builtin_amdgcn_s_setprio(0);
            }
        }
    }

    // ---- epilogue ----
    // li[qt] is lane-local for q=l31 over this lane's half of token rows; other half
    // at lane^32. O rows: q_local = (reg&3)+8*(reg>>2)+4*h5; cols hs = hst*32+l31.
    #pragma unroll
    for (int qt = 0; qt < 2; ++qt) {
        float lq = li[qt] + __shfl_xor(li[qt], 32);
        const float inv = 1.0f / lq;
        #pragma unroll
        for (int g = 0; g < 4; ++g) {
            #pragma unroll
            for (int r = 0; r < 4; ++r) {
                const int ql = g * 8 + h5 * 4 + r;
                const float iv = __shfl(inv, ql);
                const int qrow = q0 + qt * 128 + wave * 32 + ql;
                unsigned short* dst =
                    &AO[(long)(b * T_SEQ + qrow) * D_MODEL + h * 64 + l31];
                dst[0]  = f2bf(o[qt][0][g * 4 + r] * iv);
                dst[32] = f2bf(o[qt][1][g * 4 + r] * iv);
            }
        }
    }
}

// ---------------- launch ----------------
extern "C" void kernel_launch(void* const* d_in, const int* in_sizes, int n_in,
                              void* d_out, int out_size, void* d_ws, size_t ws_size,
                              hipStream_t stream) {
    const float* x   = (const float*)d_in[0];
    const float* wq  = (const float*)d_in[1];
    const float* wk  = (const float*)d_in[2];
    const float* wv  = (const float*)d_in[3];
    const float* wo  = (const float*)d_in[4];
    const float* rel = (const float*)d_in[5];

    char* ws = (char*)d_ws;
    unsigned short* Xbf = (unsigned short*)(ws);                      // 16 MiB (reused as AO)
    unsigned short* Wbf = (unsigned short*)(ws + (16l << 20));        // 8 MiB (Wq,Wk,Wv,Wo)
    unsigned short* Qb  = (unsigned short*)(ws + (24l << 20));        // Q,K,Vt contiguous 48 MiB
    // total workspace use: exactly 72 MiB

    prep<<<12288, 256, 0, stream>>>(x, wq, wk, wv, wo, Xbf, Wbf);

    // merged QKV projection: C[8192, 3072] vs concatenated [Wq;Wk;Wv]
    gemm_bt<4><<<dim3(24, 64), 256, 0, stream>>>(Xbf, Wbf, Qb);

    unsigned short* Kbf = Qb + 8388608;
    unsigned short* Vtb = Qb + 16777216;
    unsigned short* AO  = Xbf;  // X dead after the projection
    attn<<<dim3(8, 64), 256, 0, stream>>>(Qb, Kbf, Vtb, rel, AO);

    gemm_bt<3><<<dim3(8, 64), 256, 0, stream>>>(AO, Wbf + 3 * 1048576, d_out);
}

// Round 7
// 270.400 us; speedup vs baseline: 1.3057x; 1.3057x over previous
//
#include <hip/hip_runtime.h>
#include <math.h>

#define T_SEQ 2048
#define D_MODEL 1024
#define NHEADS 16
#define HSZ 64
#define BATCH 4

typedef __bf16 bf16x8 __attribute__((ext_vector_type(8)));
typedef __bf16 bf16x4 __attribute__((ext_vector_type(4)));
typedef short short4v __attribute__((ext_vector_type(4)));
typedef float f32x4 __attribute__((ext_vector_type(4)));
typedef float f32x16 __attribute__((ext_vector_type(16)));

__device__ __forceinline__ unsigned short f2bf(float f) {
    unsigned int u = __builtin_bit_cast(unsigned int, f);
    u += 0x7fff + ((u >> 16) & 1);   // RNE
    return (unsigned short)(u >> 16);
}

// pack two fp32 -> two bf16 (RNE) in one reg
__device__ __forceinline__ unsigned int pk2bf(float a, float b) {
#if __has_builtin(__builtin_amdgcn_cvt_pk_bf16_f32)
    typedef __bf16 bf16x2_t __attribute__((ext_vector_type(2)));
    bf16x2_t v = __builtin_amdgcn_cvt_pk_bf16_f32(a, b);
    return __builtin_bit_cast(unsigned int, v);
#else
    return (unsigned int)f2bf(a) | ((unsigned int)f2bf(b) << 16);
#endif
}

// raw v_exp_f32 (domain bounded; denormal flush acceptable)
__device__ __forceinline__ float fexp2(float x) {
#if __has_builtin(__builtin_amdgcn_exp2f)
    return __builtin_amdgcn_exp2f(x);
#else
    return __builtin_exp2f(x);
#endif
}

// half-swap across the lane<32 / lane>=32 boundary (T12):
// a.new = (l<32) ? a : partner(l^32).b ;  b.new = (l<32) ? partner(l^32).a : b
__device__ __forceinline__ void pl32swap(unsigned int& a, unsigned int& b) {
#if __has_builtin(__builtin_amdgcn_permlane32_swap)
    auto r = __builtin_amdgcn_permlane32_swap((int)a, (int)b, false, false);
    a = (unsigned int)r[0];
    b = (unsigned int)r[1];
#else
    unsigned int sa = (unsigned int)__shfl_xor((int)a, 32);
    unsigned int sb = (unsigned int)__shfl_xor((int)b, 32);
    const int hi = (int)((threadIdx.x & 63) >> 5);
    unsigned int na = hi ? sb : a;
    unsigned int nb = hi ? b : sa;
    a = na; b = nb;
#endif
}

__device__ __forceinline__ void gld_lds16(const void* g, void* lds) {
    __builtin_amdgcn_global_load_lds(
        (const __attribute__((address_space(1))) unsigned int*)g,
        (__attribute__((address_space(3))) unsigned int*)lds, 16, 0, 0);
}

__device__ __forceinline__ bf16x8 ld8(const unsigned short* p) {
    return *(const bf16x8*)p;
}

// T5 bucket bias (log2e-scaled), identical math to the reference bucketing.
__device__ __forceinline__ float t5_bias(int delta, int h, const float* __restrict__ rel) {
    int bucket = delta > 0 ? 16 : 0;
    int arp = delta < 0 ? -delta : delta;
    if (arp < 8) {
        bucket += arp;
    } else {
        float f = logf((float)arp / 7.0f) * (8.0f / logf(128.0f / 7.0f));
        int rl = 7 + (int)f;            // trunc == floor (f>0)
        bucket += rl < 15 ? rl : 15;
    }
    return rel[bucket * NHEADS + h] * 1.4426950408889634f;
}

// ---------------- fused prep: cast X (bf16), cast W (bf16) --------------------------
// grid: [0,8192) cast_x | [8192,12288) cast_w
__global__ void prep(const float* __restrict__ x,
                     const float* __restrict__ w0, const float* __restrict__ w1,
                     const float* __restrict__ w2, const float* __restrict__ w3,
                     unsigned short* __restrict__ Xbf,
                     unsigned short* __restrict__ Wbf) {
    int bid = blockIdx.x;
    int tid = threadIdx.x;
    if (bid < 8192) {
        int i = bid * 256 + tid;            // 2097152 float4s
        float4 v = ((const float4*)x)[i];
        ushort4 o;
        o.x = f2bf(v.x); o.y = f2bf(v.y); o.z = f2bf(v.z); o.w = f2bf(v.w);
        ((ushort4*)Xbf)[i] = o;
    } else {
        int wsel = (bid - 8192) >> 10;
        const float* srcs[4] = {w0, w1, w2, w3};
        int i = ((bid - 8192) & 1023) * 256 + tid;   // 262144 float4s per W
        float4 v = ((const float4*)srcs[wsel])[i];
        ushort4 o;
        o.x = f2bf(v.x); o.y = f2bf(v.y); o.z = f2bf(v.z); o.w = f2bf(v.w);
        ((ushort4*)(Wbf + (size_t)wsel * 1048576))[i] = o;
    }
}

// ---------------- GEMM: C[M,N] = A[M,K] * B[N,K]^T  (bf16 in, fp32 acc) -------------
// v10: double-buffered K-loop (1 barrier/kt, prefetch overlaps MFMA) + XCD-aware
// bijective block swizzle (T1). LDS 2 x 32 KB = 64 KB -> still 2 blocks/CU.
// MODE 4: merged QKV.  B = [Wq;Wk;Wv] (3072x1024).  out = Q base; K at +8M, Vt at +16M.
// MODE 3: plain fp32 [M,1024] (output projection)
template<int MODE>
__global__ __launch_bounds__(256, 2) void gemm_bt(
    const unsigned short* __restrict__ A,
    const unsigned short* __restrict__ Bw,
    void* __restrict__ out)
{
    constexpr int K = 1024;
    __shared__ __align__(16) char smem[65536];   // 2 x (As 16K + Bs 16K)

    const int tid  = threadIdx.x;
    const int wave = tid >> 6;
    const int lane = tid & 63;
    const int quad = lane >> 4;
    const int l16  = lane & 15;
    const int wm   = wave >> 1;
    const int wn   = wave & 1;

    // XCD-aware bijective swizzle: nwg % 8 == 0 in both modes.
    constexpr int NWGX = (MODE == 4) ? 24 : 8;
    const int orig = blockIdx.x + blockIdx.y * NWGX;
    constexpr int CPX = (NWGX * 64) / 8;     // chunk per XCD
    const int swz  = (orig & 7) * CPX + (orig >> 3);
    const int bn   = swz % NWGX;
    const int bm   = swz / NWGX;

    const int r_in = lane >> 3;              // 0..7
    const int lc   = (lane & 7) ^ r_in;      // swizzled 16B chunk

    f32x4 acc[4][4];
    #pragma unroll
    for (int m = 0; m < 4; ++m)
        #pragma unroll
        for (int n = 0; n < 4; ++n)
            acc[m][n] = f32x4{0.f, 0.f, 0.f, 0.f};

    const long a_row0 = (long)bm * 128;
    const long b_row0 = (long)bn * 128;

    // prologue: stage tile 0 into buffer 0
    {
        const int k0 = lc * 8;
        unsigned short* As_ = (unsigned short*)smem;
        unsigned short* Bs_ = (unsigned short*)(smem + 16384);
        #pragma unroll
        for (int c = 0; c < 4; ++c) {
            int cc = wave * 4 + c;
            int r  = cc * 8 + r_in;
            gld_lds16(A  + (a_row0 + r) * K + k0, &As_[cc * 512]);
            gld_lds16(Bw + (b_row0 + r) * K + k0, &Bs_[cc * 512]);
        }
    }

    for (int kt = 0; kt < K / 64; ++kt) {
        const int cur = kt & 1;
        __syncthreads();   // vmcnt(0): buf[cur] staged; all prev-buffer reads done

        if (kt + 1 < K / 64) {   // prefetch next K-tile into the other buffer
            const int k0 = (kt + 1) * 64 + lc * 8;
            unsigned short* As_ = (unsigned short*)(smem + (cur ^ 1) * 32768);
            unsigned short* Bs_ = (unsigned short*)(smem + (cur ^ 1) * 32768 + 16384);
            #pragma unroll
            for (int c = 0; c < 4; ++c) {
                int cc = wave * 4 + c;
                int r  = cc * 8 + r_in;
                gld_lds16(A  + (a_row0 + r) * K + k0, &As_[cc * 512]);
                gld_lds16(Bw + (b_row0 + r) * K + k0, &Bs_[cc * 512]);
            }
        }

        unsigned short* As = (unsigned short*)(smem + cur * 32768);
        unsigned short* Bs = (unsigned short*)(smem + cur * 32768 + 16384);

        bf16x8 af[4][2], bf[4][2];
        #pragma unroll
        for (int m = 0; m < 4; ++m)
            #pragma unroll
            for (int ks = 0; ks < 2; ++ks) {
                int r  = wm * 64 + m * 16 + l16;
                int pc = (ks * 4 + quad) ^ (r & 7);
                af[m][ks] = ld8(&As[r * 64 + pc * 8]);
            }
        #pragma unroll
        for (int n = 0; n < 4; ++n)
            #pragma unroll
            for (int ks = 0; ks < 2; ++ks) {
                int r  = wn * 64 + n * 16 + l16;
                int pc = (ks * 4 + quad) ^ (r & 7);
                bf[n][ks] = ld8(&Bs[r * 64 + pc * 8]);
            }
        #pragma unroll
        for (int ks = 0; ks < 2; ++ks)
            #pragma unroll
            for (int m = 0; m < 4; ++m)
                #pragma unroll
                for (int n = 0; n < 4; ++n)
                    acc[m][n] = __builtin_amdgcn_mfma_f32_16x16x32_bf16(
                        af[m][ks], bf[n][ks], acc[m][n], 0, 0, 0);
    }

    // epilogue: C/D layout col = lane&15, row = quad*4 + reg
    const int which = (MODE == 4) ? (bn >> 3) : 0;   // block-uniform: 0=Q 1=K 2=V
    if (MODE == 3) {
        float* O = (float*)out;
        #pragma unroll
        for (int m = 0; m < 4; ++m) {
            int row = bm * 128 + wm * 64 + m * 16 + quad * 4;
            #pragma unroll
            for (int n = 0; n < 4; ++n) {
                int col = bn * 128 + wn * 64 + n * 16 + l16;
                #pragma unroll
                for (int r = 0; r < 4; ++r)
                    O[(long)(row + r) * 1024 + col] = acc[m][n][r];
            }
        }
    } else if (which == 2) {
        // V: r-packed ushort4 direct to [B,NH,HS,T]
        unsigned short* O = (unsigned short*)out + (size_t)2 * 8388608;
        #pragma unroll
        for (int m = 0; m < 4; ++m) {
            int row = bm * 128 + wm * 64 + m * 16 + quad * 4;
            int b = row >> 11, t = row & 2047;
            #pragma unroll
            for (int n = 0; n < 4; ++n) {
                int cl = (bn * 128 + wn * 64 + n * 16 + l16) & 1023;
                int h = cl >> 6, hs = cl & 63;
                ushort4 pk;
                pk.x = f2bf(acc[m][n][0]); pk.y = f2bf(acc[m][n][1]);
                pk.z = f2bf(acc[m][n][2]); pk.w = f2bf(acc[m][n][3]);
                *(ushort4*)&O[(long)((b * 16 + h) * 64 + hs) * 2048 + t] = pk;
            }
        }
    } else {
        // Q/K: per-wave LDS transpose -> contiguous dwordx4 stores to [B,NH,T,HS].
        __syncthreads();   // all waves done with As/Bs k-loop reads
        unsigned short* Ew = (unsigned short*)smem + wave * 4608;   // 64 x 72-stride
        const float qs = (which == 0) ? 0.125f * 1.4426950408889634f : 1.0f;
        #pragma unroll
        for (int m = 0; m < 4; ++m)
            #pragma unroll
            for (int n = 0; n < 4; ++n)
                #pragma unroll
                for (int r = 0; r < 4; ++r)
                    Ew[(m * 16 + quad * 4 + r) * 72 + n * 16 + l16] =
                        f2bf(acc[m][n][r] * qs);
        asm volatile("s_waitcnt lgkmcnt(0)" ::: "memory");  // wave-private write->read

        const int cl0 = (bn * 128 + wn * 64) & 1023;
        const int h   = cl0 >> 6;
        const int gr0 = bm * 128 + wm * 64;
        const int b   = gr0 >> 11, t0 = gr0 & 2047;
        unsigned short* O = (unsigned short*)out + (size_t)which * 8388608
                          + ((size_t)(b * 16 + h) * 2048 + t0) * 64;
        #pragma unroll
        for (int rr = 0; rr < 8; ++rr) {
            int row   = rr * 8 + (lane >> 3);
            int chunk = lane & 7;
            uint4 v = *(const uint4*)&Ew[row * 72 + chunk * 8];
            *(uint4*)&O[(size_t)row * 64 + chunk * 8] = v;
        }
    }
}

// ---------------- flash attention v12: v9 + bias decoupled from MFMA C-init ----------
// v9 (32x32x16, permlane half-swap, tree li, 4 blocks/CU) with one change: QK MFMA
// accumulates from zero and the bias folds into the exp2 argument. This removes the
// up-to-16 serial ds_read_b32 that gated the MFMA chain via lgkmcnt; bias fetches are
// now independent work the scheduler overlaps with the MFMA cluster. Outband tiles
// touch no LDS at all. Numerics: only fp32 association order changes.
// LDS: Ks dbuf 16K + Vs dbuf 16K + Bb 1.1K = 33.8 KB.
__global__ __launch_bounds__(256, 4) void attn(
    const unsigned short* __restrict__ Q,    // [B,NH,T,HS] bf16, pre-scaled by 0.125*log2e
    const unsigned short* __restrict__ Kb,   // [B,NH,T,HS] bf16
    const unsigned short* __restrict__ Vt,   // [B,NH,HS,T] bf16
    const float* __restrict__ rel,           // [N_BUCKETS, NH] fp32 (input buffer)
    unsigned short* __restrict__ AO)         // [B,T,D] bf16
{
    __shared__ __align__(16) char smem[33824];
    unsigned short* KsB = (unsigned short*)smem;             // 2 x 8 KB (64 tok x 64 hs)
    unsigned short* VsB = (unsigned short*)(smem + 16384);   // 2 x 8 KB (64 hs x 64 tok)
    float*          Bb  = (float*)(smem + 32768);            // 263 floats delta-table

    const int tid  = threadIdx.x;
    const int wave = tid >> 6;
    const int lane = tid & 63;
    const int l31  = lane & 31;
    const int h5   = lane >> 5;

    const int bh = blockIdx.y;          // b*16 + h
    const int b  = bh >> 4, h = bh & 15;
    const int q0 = blockIdx.x * 128;

    const unsigned short* Qg = Q  + (long)bh * T_SEQ * HSZ;
    const unsigned short* Kg = Kb + (long)bh * T_SEQ * HSZ;
    const unsigned short* Vg = Vt + (long)bh * HSZ * T_SEQ;

    const int r_in = lane >> 3;
    const int lc   = (lane & 7) ^ r_in;

    // prefetch tile 0 into buffer 0
    {
        #pragma unroll
        for (int c = 0; c < 2; ++c) {
            int cc = wave * 2 + c;
            int r  = cc * 8 + r_in;
            gld_lds16(Kg + (long)r * 64 + lc * 8, &KsB[cc * 512]);
            gld_lds16(Vg + (long)r * T_SEQ + lc * 8, &VsB[cc * 512]);
        }
    }

    // delta-table: Bb[i] = bias(delta = i - 131), i in [0,263). Saturation at the
    // edges makes clamped reads bit-identical to the full sliding window.
    for (int i = tid; i < 263; i += 256)
        Bb[i] = t5_bias(i - 131, h, rel);

    // Q fragments (B-operand of 32x32x16: n=q=l31, k=(l>>5)*8+j, per hsc slice of 16)
    const int qrow_lane = q0 + wave * 32 + l31;
    bf16x8 qf[4];
    #pragma unroll
    for (int hsc = 0; hsc < 4; ++hsc)
        qf[hsc] = ld8(&Qg[(long)qrow_lane * 64 + hsc * 16 + h5 * 8]);

    f32x16 o0 = {0.f,0.f,0.f,0.f,0.f,0.f,0.f,0.f,0.f,0.f,0.f,0.f,0.f,0.f,0.f,0.f};
    f32x16 o1 = o0;
    float li = 0.0f;

    // saturated buckets: delta <= -128 -> bucket 15; delta >= +128 -> bucket 31
    const float cneg = rel[15 * NHEADS + h] * 1.4426950408889634f;
    const float cpos = rel[31 * NHEADS + h] * 1.4426950408889634f;

    for (int kt = 0; kt < T_SEQ / 64; ++kt) {
        const int cur = kt & 1;
        __syncthreads();   // vmcnt(0): cur buffer staged; all prev-buffer reads done

        if (kt + 1 < T_SEQ / 64) {          // prefetch next tile into other buffer
            unsigned short* Kn = KsB + (cur ^ 1) * 4096;
            unsigned short* Vn = VsB + (cur ^ 1) * 4096;
            #pragma unroll
            for (int c = 0; c < 2; ++c) {
                int cc = wave * 2 + c;
                int r  = cc * 8 + r_in;
                gld_lds16(Kg + (long)((kt + 1) * 64 + r) * 64 + lc * 8, &Kn[cc * 512]);
                gld_lds16(Vg + (long)r * T_SEQ + (kt + 1) * 64 + lc * 8, &Vn[cc * 512]);
            }
        }

        const unsigned short* Ks = KsB + cur * 4096;
        const unsigned short* Vs = VsB + cur * 4096;

        // T5 saturation: tile-uniform bias when whole delta range is saturated
        const int lo = kt * 64 - q0 - 127;       // min delta this (block, kt)
        const int hi = kt * 64 + 63 - q0;        // max delta
        const bool outband = (lo >= 128) || (hi <= -128);
        const float cb = (lo >= 128) ? cpos : cneg;

        #pragma unroll
        for (int tt = 0; tt < 2; ++tt) {
            // ---- K fragments: row tok = tt*32 + l31, 16B chunk (hsc*2+h5)^(row&7) ----
            const int rk = tt * 32 + l31;
            bf16x8 af[4];
            #pragma unroll
            for (int hsc = 0; hsc < 4; ++hsc)
                af[hsc] = ld8(&Ks[rk * 64 + (((hsc << 1) | h5) ^ (rk & 7)) * 8]);

            // ---- bias values (independent of MFMA chain; overlaps it) ----
            float bb[16];
            if (outband) {
                #pragma unroll
                for (int e = 0; e < 16; ++e) bb[e] = cb;
            } else {
                const int ibase = kt * 64 + tt * 32 + h5 * 4 + 131 - qrow_lane;
                #pragma unroll
                for (int g = 0; g < 4; ++g) {
                    int i0 = ibase + g * 8;
                    i0 = i0 < 0 ? 0 : (i0 > 259 ? 259 : i0);
                    #pragma unroll
                    for (int r = 0; r < 4; ++r) bb[g * 4 + r] = Bb[i0 + r];
                }
            }

            // ---- St = K Q^T (zero C-init) ----
            f32x16 s = {0.f,0.f,0.f,0.f,0.f,0.f,0.f,0.f,
                        0.f,0.f,0.f,0.f,0.f,0.f,0.f,0.f};
            __builtin_amdgcn_s_setprio(1);
            #pragma unroll
            for (int hsc = 0; hsc < 4; ++hsc)
                s = __builtin_amdgcn_mfma_f32_32x32x16_bf16(af[hsc], qf[hsc], s, 0, 0, 0);
            __builtin_amdgcn_s_setprio(0);

            // ---- softmax numerators (bias folded into exp2 argument) ----
            float p[16];
            #pragma unroll
            for (int e = 0; e < 16; ++e) p[e] = fexp2(s[e] + bb[e]);
            {   // 4-deep tree, single dependent add into li per tile
                float t0 = (p[0]  + p[1])  + (p[2]  + p[3]);
                float t1 = (p[4]  + p[5])  + (p[6]  + p[7]);
                float t2 = (p[8]  + p[9])  + (p[10] + p[11]);
                float t3 = (p[12] + p[13]) + (p[14] + p[15]);
                li += (t0 + t1) + (t2 + t3);
            }

            // ---- pack + half-swap into PV A-frags (tokens tc*16 + h5*8 + j) ----
            unsigned int x0 = pk2bf(p[0],  p[1]),  x1 = pk2bf(p[2],  p[3]);
            unsigned int y0 = pk2bf(p[4],  p[5]),  y1 = pk2bf(p[6],  p[7]);
            unsigned int z0 = pk2bf(p[8],  p[9]),  z1 = pk2bf(p[10], p[11]);
            unsigned int u0 = pk2bf(p[12], p[13]), u1 = pk2bf(p[14], p[15]);
            pl32swap(x0, y0); pl32swap(x1, y1);
            pl32swap(z0, u0); pl32swap(z1, u1);
            uint4 pw0 = {x0, x1, y0, y1};
            uint4 pw1 = {z0, z1, u0, u1};
            bf16x8 pf[2] = {__builtin_bit_cast(bf16x8, pw0),
                            __builtin_bit_cast(bf16x8, pw1)};

            // ---- O += P V (tc = tt*2 + c; vf: n=hs=l31, k=tok chunk (tc*2+h5)) ----
            #pragma unroll
            for (int c = 0; c < 2; ++c) {
                const int tc = tt * 2 + c;
                const int rv0 = l31;          // hst = 0
                const int rv1 = 32 + l31;     // hst = 1
                bf16x8 vf0 = ld8(&Vs[rv0 * 64 + (((tc << 1) | h5) ^ (rv0 & 7)) * 8]);
                bf16x8 vf1 = ld8(&Vs[rv1 * 64 + (((tc << 1) | h5) ^ (rv1 & 7)) * 8]);
                __builtin_amdgcn_s_setprio(1);
                o0 = __builtin_amdgcn_mfma_f32_32x32x16_bf16(pf[c], vf0, o0, 0, 0, 0);
                o1 = __builtin_amdgcn_mfma_f32_32x32x16_bf16(pf[c], vf1, o1, 0, 0, 0);
                __builtin_amdgcn_s_setprio(0);
            }
        }
    }

    // ---- epilogue ----
    li += __shfl_xor(li, 32);
    const float inv = 1.0f / li;

    // O rows: q_local = (reg&3) + 8*(reg>>2) + 4*h5; cols hs = hst*32 + l31.
    #pragma unroll
    for (int g = 0; g < 4; ++g) {
        #pragma unroll
        for (int r = 0; r < 4; ++r) {
            const int ql = g * 8 + h5 * 4 + r;
            const float iv = __shfl(inv, ql);
            const int qrow = q0 + wave * 32 + ql;
            unsigned short* dst =
                &AO[(long)(b * T_SEQ + qrow) * D_MODEL + h * 64 + l31];
            dst[0]  = f2bf(o0[g * 4 + r] * iv);
            dst[32] = f2bf(o1[g * 4 + r] * iv);
        }
    }
}

// ---------------- launch ----------------
extern "C" void kernel_launch(void* const* d_in, const int* in_sizes, int n_in,
                              void* d_out, int out_size, void* d_ws, size_t ws_size,
                              hipStream_t stream) {
    const float* x   = (const float*)d_in[0];
    const float* wq  = (const float*)d_in[1];
    const float* wk  = (const float*)d_in[2];
    const float* wv  = (const float*)d_in[3];
    const float* wo  = (const float*)d_in[4];
    const float* rel = (const float*)d_in[5];

    char* ws = (char*)d_ws;
    unsigned short* Xbf = (unsigned short*)(ws);                      // 16 MiB (reused as AO)
    unsigned short* Wbf = (unsigned short*)(ws + (16l << 20));        // 8 MiB (Wq,Wk,Wv,Wo)
    unsigned short* Qb  = (unsigned short*)(ws + (24l << 20));        // Q,K,Vt contiguous 48 MiB
    // total workspace use: exactly 72 MiB

    prep<<<12288, 256, 0, stream>>>(x, wq, wk, wv, wo, Xbf, Wbf);

    // merged QKV projection: C[8192, 3072] vs concatenated [Wq;Wk;Wv]
    gemm_bt<4><<<dim3(24, 64), 256, 0, stream>>>(Xbf, Wbf, Qb);

    unsigned short* Kbf = Qb + 8388608;
    unsigned short* Vtb = Qb + 16777216;
    unsigned short* AO  = Xbf;  // X dead after the projection
    attn<<<dim3(16, 64), 256, 0, stream>>>(Qb, Kbf, Vtb, rel, AO);

    gemm_bt<3><<<dim3(8, 64), 256, 0, stream>>>(AO, Wbf + 3 * 1048576, d_out);
}